// Round 1
// baseline (752.474 us; speedup 1.0000x reference)
//
#include <hip/hip_runtime.h>
#include <math.h>
#include <float.h>

// Problem constants
#define KN 65536            // rows of z
#define KK 256              // rows of mu (= columns of d)
#define KD 256              // feature dim
#define KNK (65536LL * 256LL)
#define EPS_C 1e-6f
#define TARGET_Z 1.3219280948873622f  /* log2(5) - 1 */
#define TARGET_U 2.3219280948873622f  /* log2(5)     */

// ---------------- helpers ----------------

__device__ __forceinline__ void ins5(float v, float& t0, float& t1, float& t2,
                                     float& t3, float& t4) {
    if (v < t4) {
        t4 = v; float tmp;
        if (t4 < t3) { tmp = t3; t3 = t4; t4 = tmp; }
        if (t3 < t2) { tmp = t2; t2 = t3; t3 = tmp; }
        if (t2 < t1) { tmp = t1; t1 = t2; t2 = tmp; }
        if (t1 < t0) { tmp = t0; t0 = t1; t1 = tmp; }
    }
}

// Replicates the reference bisection exactly: lo=0, hi=1e4, sigma0=1, 150 iters.
// g1..g4 are rel[j]-rho (>=0); the rho term contributes exp(0)=1.
__device__ __forceinline__ float bisect_sigma(float g1, float g2, float g3,
                                              float g4, float target) {
    float lo = 0.f, hi = 10000.f, sigma = 1.f;
    #pragma unroll 1
    for (int it = 0; it < 150; ++it) {
        float inv = 1.f / sigma;
        float s = 1.f + expf(-g1 * inv) + expf(-g2 * inv) +
                  expf(-g3 * inv) + expf(-g4 * inv);
        if (s > target) hi = sigma; else lo = sigma;
        sigma = 0.5f * (lo + hi);
    }
    return sigma;
}

// ---------------- kernels ----------------

// Per-row sum and sum-of-squares (one wave per row). rows columns = 256 floats.
__global__ __launch_bounds__(256) void row_stats(const float* __restrict__ x,
                                                 float* __restrict__ xs,
                                                 float* __restrict__ x2) {
    int wave = threadIdx.x >> 6, lane = threadIdx.x & 63;
    int row = blockIdx.x * 4 + wave;
    const float4* p = (const float4*)(x + (size_t)row * KD);
    float4 v = p[lane];
    float s = v.x + v.y + v.z + v.w;
    float q = v.x * v.x + v.y * v.y + v.z * v.z + v.w * v.w;
    #pragma unroll
    for (int off = 32; off > 0; off >>= 1) {
        s += __shfl_down(s, off, 64);
        q += __shfl_down(q, off, 64);
    }
    if (lane == 0) { xs[row] = s; x2[row] = q; }
}

// d[r][c] = sqrt(max(z2[r]+m2[c]-2*dot(z_r,mu_c)+2eps*(zs[r]-ms[c])+KD*eps^2, 0))
// 128x128 tile, 256 threads, 8x8 microtile, BK=16.
__global__ __launch_bounds__(256) void dist_gemm(const float* __restrict__ z,
                                                 const float* __restrict__ mu,
                                                 const float* __restrict__ zs,
                                                 const float* __restrict__ z2,
                                                 const float* __restrict__ ms,
                                                 const float* __restrict__ m2,
                                                 float* __restrict__ dout) {
    __shared__ __align__(16) float As[16][132];
    __shared__ __align__(16) float Bs[16][132];
    int tid = threadIdx.x;
    int r0 = blockIdx.y * 128;
    int c0 = blockIdx.x * 128;
    int tx = tid & 15, ty = tid >> 4;
    float acc[8][8];
    #pragma unroll
    for (int i = 0; i < 8; ++i)
        #pragma unroll
        for (int j = 0; j < 8; ++j) acc[i][j] = 0.f;

    for (int kk = 0; kk < KD; kk += 16) {
        #pragma unroll
        for (int i = 0; i < 2; ++i) {
            int f = tid + 256 * i;          // 0..511
            int row = f >> 2, q = f & 3;    // 128 rows x 4 quads
            float4 va = *(const float4*)(z + (size_t)(r0 + row) * KD + kk + 4 * q);
            As[4 * q + 0][row] = va.x; As[4 * q + 1][row] = va.y;
            As[4 * q + 2][row] = va.z; As[4 * q + 3][row] = va.w;
            float4 vb = *(const float4*)(mu + (size_t)(c0 + row) * KD + kk + 4 * q);
            Bs[4 * q + 0][row] = vb.x; Bs[4 * q + 1][row] = vb.y;
            Bs[4 * q + 2][row] = vb.z; Bs[4 * q + 3][row] = vb.w;
        }
        __syncthreads();
        #pragma unroll
        for (int k = 0; k < 16; ++k) {
            float4 a0 = *(const float4*)&As[k][ty * 8];
            float4 a1 = *(const float4*)&As[k][ty * 8 + 4];
            float4 b0 = *(const float4*)&Bs[k][tx * 8];
            float4 b1 = *(const float4*)&Bs[k][tx * 8 + 4];
            float a[8] = {a0.x, a0.y, a0.z, a0.w, a1.x, a1.y, a1.z, a1.w};
            float b[8] = {b0.x, b0.y, b0.z, b0.w, b1.x, b1.y, b1.z, b1.w};
            #pragma unroll
            for (int i = 0; i < 8; ++i)
                #pragma unroll
                for (int j = 0; j < 8; ++j) acc[i][j] += a[i] * b[j];
        }
        __syncthreads();
    }
    #pragma unroll
    for (int i = 0; i < 8; ++i) {
        int r = r0 + ty * 8 + i;
        float z2r = z2[r], zsr = zs[r];
        float out[8];
        #pragma unroll
        for (int j = 0; j < 8; ++j) {
            int c = c0 + tx * 8 + j;
            float d2 = z2r + m2[c] - 2.f * acc[i][j] +
                       2.f * EPS_C * (zsr - ms[c]) + (float)KD * EPS_C * EPS_C;
            out[j] = sqrtf(fmaxf(d2, 0.f));
        }
        float4* dst = (float4*)(dout + (size_t)r * KK + c0 + tx * 8);
        dst[0] = make_float4(out[0], out[1], out[2], out[3]);
        dst[1] = make_float4(out[4], out[5], out[6], out[7]);
    }
}

// Per-row top-5 + bisection -> rho_z, inv_sigma_z. Thread per row.
__global__ __launch_bounds__(256) void row_top5_sigma(const float* __restrict__ d,
                                                      float* __restrict__ rho_z,
                                                      float* __restrict__ isz) {
    int row = blockIdx.x * 256 + threadIdx.x;
    const float4* p = (const float4*)(d + (size_t)row * KK);
    float t0 = FLT_MAX, t1 = FLT_MAX, t2 = FLT_MAX, t3 = FLT_MAX, t4 = FLT_MAX;
    #pragma unroll 8
    for (int j = 0; j < KK / 4; ++j) {
        float4 v = p[j];
        ins5(v.x, t0, t1, t2, t3, t4); ins5(v.y, t0, t1, t2, t3, t4);
        ins5(v.z, t0, t1, t2, t3, t4); ins5(v.w, t0, t1, t2, t3, t4);
    }
    float sigma = bisect_sigma(t1 - t0, t2 - t0, t3 - t0, t4 - t0, TARGET_Z);
    rho_z[row] = t0;
    isz[row] = 1.f / sigma;
}

// Per-column partial top-5 over a 256-row stripe. Block b -> rows [256b,256b+256).
// Thread t owns column t. partials layout: [(c*256 + b)*5 + j].
__global__ __launch_bounds__(256) void col_partial_top5(const float* __restrict__ d,
                                                        float* __restrict__ partials) {
    int b = blockIdx.x, t = threadIdx.x;
    size_t base = (size_t)b * 256 * KK + t;
    float t0 = FLT_MAX, t1 = FLT_MAX, t2 = FLT_MAX, t3 = FLT_MAX, t4 = FLT_MAX;
    #pragma unroll 8
    for (int r = 0; r < 256; ++r) ins5(d[base + (size_t)r * KK], t0, t1, t2, t3, t4);
    float* out = partials + ((size_t)t * 256 + b) * 5;
    out[0] = t0; out[1] = t1; out[2] = t2; out[3] = t3; out[4] = t4;
}

// Merge 256 partial top-5 lists per column + bisection -> rho_u, inv_sigma_u.
__global__ __launch_bounds__(64) void col_sigma(const float* __restrict__ partials,
                                                float* __restrict__ rho_u,
                                                float* __restrict__ isu) {
    int c = blockIdx.x * 64 + threadIdx.x;
    const float4* p = (const float4*)(partials + (size_t)c * 1280);
    float t0 = FLT_MAX, t1 = FLT_MAX, t2 = FLT_MAX, t3 = FLT_MAX, t4 = FLT_MAX;
    #pragma unroll 4
    for (int i = 0; i < 320; ++i) {
        float4 v = p[i];
        ins5(v.x, t0, t1, t2, t3, t4); ins5(v.y, t0, t1, t2, t3, t4);
        ins5(v.z, t0, t1, t2, t3, t4); ins5(v.w, t0, t1, t2, t3, t4);
    }
    float sigma = bisect_sigma(t1 - t0, t2 - t0, t3 - t0, t4 - t0, TARGET_U);
    rho_u[c] = t0;
    isu[c] = 1.f / sigma;
}

// Per-row sum of Su = W1 + W2 - W1*W2 -> inv_rowsum. Thread per row.
__global__ __launch_bounds__(256) void rowsum_su(const float* __restrict__ d,
                                                 const float* __restrict__ rho_z,
                                                 const float* __restrict__ isz,
                                                 const float* __restrict__ rho_u,
                                                 const float* __restrict__ isu,
                                                 float* __restrict__ irowsum) {
    int row = blockIdx.x * 256 + threadIdx.x;
    float rz = rho_z[row], sz = isz[row];
    const float4* p = (const float4*)(d + (size_t)row * KK);
    const float4* RU = (const float4*)rho_u;
    const float4* IU = (const float4*)isu;
    float sum = 0.f;
    #pragma unroll 4
    for (int j = 0; j < KK / 4; ++j) {
        float4 v = p[j], ru = RU[j], iu = IU[j];
        float w1, w2;
        w1 = expf(-fmaxf(v.x - rz, 0.f) * sz); w2 = expf(-fmaxf(v.x - ru.x, 0.f) * iu.x);
        sum += w1 + w2 - w1 * w2;
        w1 = expf(-fmaxf(v.y - rz, 0.f) * sz); w2 = expf(-fmaxf(v.y - ru.y, 0.f) * iu.y);
        sum += w1 + w2 - w1 * w2;
        w1 = expf(-fmaxf(v.z - rz, 0.f) * sz); w2 = expf(-fmaxf(v.z - ru.z, 0.f) * iu.z);
        sum += w1 + w2 - w1 * w2;
        w1 = expf(-fmaxf(v.w - rz, 0.f) * sz); w2 = expf(-fmaxf(v.w - ru.w, 0.f) * iu.w);
        sum += w1 + w2 - w1 * w2;
    }
    irowsum[row] = 1.f / sum;
}

// Column-oriented streaming pass: writes W1 (out0, out2), S (out1), atomic colsum.
// Block handles 64 rows; thread t owns column t.
__global__ __launch_bounds__(256) void w1_s_pass(const float* __restrict__ d,
                                                 const float* __restrict__ rho_z,
                                                 const float* __restrict__ isz,
                                                 const float* __restrict__ rho_u,
                                                 const float* __restrict__ isu,
                                                 const float* __restrict__ irowsum,
                                                 float* __restrict__ out0,
                                                 float* __restrict__ out1,
                                                 float* __restrict__ out2,
                                                 float* __restrict__ colsum) {
    int t = threadIdx.x;
    int r0 = blockIdx.x * 64;
    float ru = rho_u[t], iu = isu[t];
    float csum = 0.f;
    for (int r = 0; r < 64; ++r) {
        int row = r0 + r;
        size_t idx = (size_t)row * KK + t;
        float dv = d[idx];
        float rz = rho_z[row], sz = isz[row], ir = irowsum[row];
        float w1 = expf(-fmaxf(dv - rz, 0.f) * sz);
        float w2 = expf(-fmaxf(dv - ru, 0.f) * iu);
        float su = w1 + w2 - w1 * w2;
        float s = su * ir;
        out0[idx] = w1;
        out2[idx] = w1;
        out1[idx] = s;
        csum += s;
    }
    atomicAdd(&colsum[t], csum);
}

__global__ __launch_bounds__(256) void invert256(const float* __restrict__ colsum,
                                                 float* __restrict__ icol) {
    int t = threadIdx.x;
    icol[t] = 1.f / colsum[t];
}

// Per-row sum of Dp = S^2 * icol[c] -> inv_rowsumD. Thread per row.
__global__ __launch_bounds__(256) void rowsum_d(const float* __restrict__ S,
                                                const float* __restrict__ icol,
                                                float* __restrict__ irowD) {
    int row = blockIdx.x * 256 + threadIdx.x;
    const float4* p = (const float4*)(S + (size_t)row * KK);
    const float4* IC = (const float4*)icol;
    float sum = 0.f;
    #pragma unroll 4
    for (int j = 0; j < KK / 4; ++j) {
        float4 v = p[j], ic = IC[j];
        sum += v.x * v.x * ic.x + v.y * v.y * ic.y +
               v.z * v.z * ic.z + v.w * v.w * ic.w;
    }
    irowD[row] = 1.f / sum;
}

// Final Dmat = S^2 * icol[c] * irowD[row] -> out3 (overwrites d scratch).
__global__ __launch_bounds__(256) void dmat_pass(const float* __restrict__ S,
                                                 const float* __restrict__ icol,
                                                 const float* __restrict__ irowD,
                                                 float* __restrict__ out3) {
    int t = threadIdx.x;
    int r0 = blockIdx.x * 64;
    float ic = icol[t];
    for (int r = 0; r < 64; ++r) {
        int row = r0 + r;
        size_t idx = (size_t)row * KK + t;
        float s = S[idx];
        out3[idx] = s * s * ic * irowD[row];
    }
}

// ---------------- launch ----------------

extern "C" void kernel_launch(void* const* d_in, const int* in_sizes, int n_in,
                              void* d_out, int out_size, void* d_ws, size_t ws_size,
                              hipStream_t stream) {
    const float* z  = (const float*)d_in[0];
    const float* mu = (const float*)d_in[1];
    // d_in[2] = epoch (unused by the reference computation)

    float* out = (float*)d_out;
    float* out0 = out;                 // W1
    float* out1 = out + KNK;           // S
    float* out2 = out + 2 * KNK;       // W1 (again)
    float* out3 = out + 3 * KNK;       // Dmat — used as scratch for d first

    float* w = (float*)d_ws;
    float* zs       = w;                        // KN
    float* z2       = w + KN;                   // KN
    float* rho_z    = w + 2 * (size_t)KN;       // KN
    float* isz      = w + 3 * (size_t)KN;       // KN
    float* irowsum  = w + 4 * (size_t)KN;       // KN
    float* irowD    = w + 5 * (size_t)KN;       // KN
    float* ms       = w + 6 * (size_t)KN;       // KK
    float* m2       = ms + KK;                  // KK
    float* rho_u    = m2 + KK;                  // KK
    float* isu      = rho_u + KK;               // KK
    float* colsum   = isu + KK;                 // KK
    float* icol     = colsum + KK;              // KK
    float* partials = icol + KK + 256;          // 256*256*5 floats (16B aligned)

    float* dmat = out3;  // pairwise distance scratch lives in the Dmat slot

    hipMemsetAsync(colsum, 0, KK * sizeof(float), stream);

    row_stats<<<KN / 4, 256, 0, stream>>>(z, zs, z2);
    row_stats<<<KK / 4, 256, 0, stream>>>(mu, ms, m2);

    dist_gemm<<<dim3(KK / 128, KN / 128), 256, 0, stream>>>(z, mu, zs, z2, ms, m2, dmat);

    row_top5_sigma<<<KN / 256, 256, 0, stream>>>(dmat, rho_z, isz);

    col_partial_top5<<<KN / 256, 256, 0, stream>>>(dmat, partials);
    col_sigma<<<KK / 64, 64, 0, stream>>>(partials, rho_u, isu);

    rowsum_su<<<KN / 256, 256, 0, stream>>>(dmat, rho_z, isz, rho_u, isu, irowsum);

    w1_s_pass<<<KN / 64, 256, 0, stream>>>(dmat, rho_z, isz, rho_u, isu, irowsum,
                                           out0, out1, out2, colsum);

    invert256<<<1, 256, 0, stream>>>(colsum, icol);

    rowsum_d<<<KN / 256, 256, 0, stream>>>(out1, icol, irowD);

    dmat_pass<<<KN / 64, 256, 0, stream>>>(out1, icol, irowD, out3);
}

// Round 2
// 613.438 us; speedup vs baseline: 1.2267x; 1.2267x over previous
//
#include <hip/hip_runtime.h>
#include <math.h>
#include <float.h>

#define KN 65536
#define KK 256
#define KD 256
#define KNK (65536LL * 256LL)
#define EPS_C 1e-6f
#define TARGET_Z 1.3219280948873622f  /* log2(5) - 1 */
#define TARGET_U 2.3219280948873622f  /* log2(5)     */

#define AS_LD 68
#define BS_LD 260

// ---------------- helpers ----------------

__device__ __forceinline__ void ins5(float v, float& t0, float& t1, float& t2,
                                     float& t3, float& t4) {
    if (v < t4) {
        t4 = v; float tmp;
        if (t4 < t3) { tmp = t3; t3 = t4; t4 = tmp; }
        if (t3 < t2) { tmp = t2; t2 = t3; t3 = tmp; }
        if (t2 < t1) { tmp = t1; t1 = t2; t2 = tmp; }
        if (t1 < t0) { tmp = t0; t0 = t1; t1 = tmp; }
    }
}

// Reference bisection: lo=0, hi=1e4, sigma0=1, 150 iters (k*30, k=5).
__device__ __forceinline__ float bisect_sigma(float g1, float g2, float g3,
                                              float g4, float target) {
    float lo = 0.f, hi = 10000.f, sigma = 1.f;
    #pragma unroll 1
    for (int it = 0; it < 150; ++it) {
        float inv = 1.f / sigma;
        float s = 1.f + __expf(-g1 * inv) + __expf(-g2 * inv) +
                  __expf(-g3 * inv) + __expf(-g4 * inv);
        if (s > target) hi = sigma; else lo = sigma;
        sigma = 0.5f * (lo + hi);
    }
    return sigma;
}

// ---------------- kernels ----------------

__global__ __launch_bounds__(256) void row_stats(const float* __restrict__ x,
                                                 float* __restrict__ xs,
                                                 float* __restrict__ x2) {
    int wave = threadIdx.x >> 6, lane = threadIdx.x & 63;
    int row = blockIdx.x * 4 + wave;
    const float4* p = (const float4*)(x + (size_t)row * KD);
    float4 v = p[lane];
    float s = v.x + v.y + v.z + v.w;
    float q = v.x * v.x + v.y * v.y + v.z * v.z + v.w * v.w;
    #pragma unroll
    for (int off = 32; off > 0; off >>= 1) {
        s += __shfl_down(s, off, 64);
        q += __shfl_down(q, off, 64);
    }
    if (lane == 0) { xs[row] = s; x2[row] = q; }
}

// Fused: 64x256 distance tile (full row width) + d write + row top-5 + row bisection.
// Thread (tx=tid&31, ty=tid>>5): rows r0+ty*8+i, cols {4tx+j} u {128+4tx+j}.
__global__ __launch_bounds__(256, 2) void dist_fused(
    const float* __restrict__ z, const float* __restrict__ mu,
    const float* __restrict__ zs, const float* __restrict__ z2,
    const float* __restrict__ ms, const float* __restrict__ m2,
    float* __restrict__ dout, float* __restrict__ rho_z,
    float* __restrict__ isz) {
    __shared__ __align__(16) float As[32 * AS_LD];
    __shared__ __align__(16) float Bs[32 * BS_LD];
    int tid = threadIdx.x;
    int r0 = blockIdx.x * 64;
    int tx = tid & 31, ty = tid >> 5;
    float acc[8][8];
    #pragma unroll
    for (int i = 0; i < 8; ++i)
        #pragma unroll
        for (int j = 0; j < 8; ++j) acc[i][j] = 0.f;

    for (int kk = 0; kk < KD; kk += 32) {
        #pragma unroll
        for (int i = 0; i < 2; ++i) {          // stage A: 64 rows x 32 k (transposed)
            int f = tid + 256 * i;
            int row = f >> 3, q = f & 7;
            float4 v = *(const float4*)(z + (size_t)(r0 + row) * KD + kk + 4 * q);
            As[(4 * q + 0) * AS_LD + row] = v.x;
            As[(4 * q + 1) * AS_LD + row] = v.y;
            As[(4 * q + 2) * AS_LD + row] = v.z;
            As[(4 * q + 3) * AS_LD + row] = v.w;
        }
        #pragma unroll
        for (int i = 0; i < 8; ++i) {          // stage B: 256 cols x 32 k (transposed)
            int f = tid + 256 * i;
            int col = f >> 3, q = f & 7;
            float4 v = *(const float4*)(mu + (size_t)col * KD + kk + 4 * q);
            Bs[(4 * q + 0) * BS_LD + col] = v.x;
            Bs[(4 * q + 1) * BS_LD + col] = v.y;
            Bs[(4 * q + 2) * BS_LD + col] = v.z;
            Bs[(4 * q + 3) * BS_LD + col] = v.w;
        }
        __syncthreads();
        #pragma unroll
        for (int k = 0; k < 32; ++k) {
            float4 a0 = *(const float4*)&As[k * AS_LD + ty * 8];
            float4 a1 = *(const float4*)&As[k * AS_LD + ty * 8 + 4];
            float4 b0 = *(const float4*)&Bs[k * BS_LD + tx * 4];
            float4 b1 = *(const float4*)&Bs[k * BS_LD + 128 + tx * 4];
            float a[8] = {a0.x, a0.y, a0.z, a0.w, a1.x, a1.y, a1.z, a1.w};
            float b[8] = {b0.x, b0.y, b0.z, b0.w, b1.x, b1.y, b1.z, b1.w};
            #pragma unroll
            for (int i = 0; i < 8; ++i)
                #pragma unroll
                for (int j = 0; j < 8; ++j) acc[i][j] += a[i] * b[j];
        }
        __syncthreads();
    }

    int c0 = 4 * tx, c1 = 128 + 4 * tx;
    float4 m2a = *(const float4*)(m2 + c0);
    float4 m2b = *(const float4*)(m2 + c1);
    float4 msa = *(const float4*)(ms + c0);
    float4 msb = *(const float4*)(ms + c1);
    float m2v[8] = {m2a.x, m2a.y, m2a.z, m2a.w, m2b.x, m2b.y, m2b.z, m2b.w};
    float msv[8] = {msa.x, msa.y, msa.z, msa.w, msb.x, msb.y, msb.z, msb.w};

    float s0 = 0.f, s1 = 0.f, s2 = 0.f, s3 = 0.f, s4 = 0.f;
    #pragma unroll
    for (int i = 0; i < 8; ++i) {
        int r = r0 + ty * 8 + i;
        float z2r = z2[r], zsr = zs[r];
        float dv[8];
        #pragma unroll
        for (int j = 0; j < 8; ++j) {
            float d2 = z2r + m2v[j] - 2.f * acc[i][j] +
                       2.f * EPS_C * (zsr - msv[j]) + (float)KD * EPS_C * EPS_C;
            dv[j] = sqrtf(fmaxf(d2, 0.f));
        }
        *(float4*)(dout + (size_t)r * KK + c0) = make_float4(dv[0], dv[1], dv[2], dv[3]);
        *(float4*)(dout + (size_t)r * KK + c1) = make_float4(dv[4], dv[5], dv[6], dv[7]);
        // row top-5: local then butterfly across the 32 tx-lanes (same half-wave)
        float t0 = FLT_MAX, t1 = FLT_MAX, t2 = FLT_MAX, t3 = FLT_MAX, t4 = FLT_MAX;
        #pragma unroll
        for (int j = 0; j < 8; ++j) ins5(dv[j], t0, t1, t2, t3, t4);
        #pragma unroll
        for (int m = 1; m < 32; m <<= 1) {
            float u0 = __shfl_xor(t0, m, 64), u1 = __shfl_xor(t1, m, 64);
            float u2 = __shfl_xor(t2, m, 64), u3 = __shfl_xor(t3, m, 64);
            float u4 = __shfl_xor(t4, m, 64);
            ins5(u0, t0, t1, t2, t3, t4); ins5(u1, t0, t1, t2, t3, t4);
            ins5(u2, t0, t1, t2, t3, t4); ins5(u3, t0, t1, t2, t3, t4);
            ins5(u4, t0, t1, t2, t3, t4);
        }
        if (tx == i) { s0 = t0; s1 = t1; s2 = t2; s3 = t3; s4 = t4; }
    }
    if (tx < 8) {
        int r = r0 + ty * 8 + tx;
        float sigma = bisect_sigma(s1 - s0, s2 - s0, s3 - s0, s4 - s0, TARGET_Z);
        rho_z[r] = s0;
        isz[r] = 1.f / sigma;
    }
}

// Per-column partial top-5 over a 256-row stripe, coalesced float4.
// partials[(col*256 + stripe)*5 + j].
__global__ __launch_bounds__(256) void col_partial(const float* __restrict__ d,
                                                   float* __restrict__ partials) {
    __shared__ float sm[4][64][20];
    int tid = threadIdx.x;
    int w = tid >> 6, l = tid & 63;
    int rbase = blockIdx.x * 256 + w * 64;
    float t[4][5];
    #pragma unroll
    for (int c = 0; c < 4; ++c)
        #pragma unroll
        for (int j = 0; j < 5; ++j) t[c][j] = FLT_MAX;
    for (int r = 0; r < 64; ++r) {
        float4 v = *(const float4*)(d + (size_t)(rbase + r) * KK + 4 * l);
        ins5(v.x, t[0][0], t[0][1], t[0][2], t[0][3], t[0][4]);
        ins5(v.y, t[1][0], t[1][1], t[1][2], t[1][3], t[1][4]);
        ins5(v.z, t[2][0], t[2][1], t[2][2], t[2][3], t[2][4]);
        ins5(v.w, t[3][0], t[3][1], t[3][2], t[3][3], t[3][4]);
    }
    #pragma unroll
    for (int c = 0; c < 4; ++c)
        #pragma unroll
        for (int j = 0; j < 5; ++j) sm[w][l][c * 5 + j] = t[c][j];
    __syncthreads();
    if (tid < 64) {
        #pragma unroll
        for (int c = 0; c < 4; ++c) {
            float p0 = sm[0][tid][c * 5 + 0], p1 = sm[0][tid][c * 5 + 1];
            float p2 = sm[0][tid][c * 5 + 2], p3 = sm[0][tid][c * 5 + 3];
            float p4 = sm[0][tid][c * 5 + 4];
            #pragma unroll
            for (int w2 = 1; w2 < 4; ++w2)
                #pragma unroll
                for (int j = 0; j < 5; ++j)
                    ins5(sm[w2][tid][c * 5 + j], p0, p1, p2, p3, p4);
            float* out = partials + ((size_t)(4 * tid + c) * 256 + blockIdx.x) * 5;
            out[0] = p0; out[1] = p1; out[2] = p2; out[3] = p3; out[4] = p4;
        }
    }
}

// One block per column: merge 256 stripe-partials + bisection.
__global__ __launch_bounds__(64) void col_sigma(const float* __restrict__ partials,
                                                float* __restrict__ rho_u,
                                                float* __restrict__ isu) {
    int c = blockIdx.x, l = threadIdx.x;
    const float* p = partials + (size_t)c * 1280 + l * 20;
    float t0 = FLT_MAX, t1 = FLT_MAX, t2 = FLT_MAX, t3 = FLT_MAX, t4 = FLT_MAX;
    #pragma unroll
    for (int i = 0; i < 5; ++i) {
        float4 v = *(const float4*)(p + 4 * i);
        ins5(v.x, t0, t1, t2, t3, t4); ins5(v.y, t0, t1, t2, t3, t4);
        ins5(v.z, t0, t1, t2, t3, t4); ins5(v.w, t0, t1, t2, t3, t4);
    }
    #pragma unroll
    for (int m = 1; m < 64; m <<= 1) {
        float u0 = __shfl_xor(t0, m, 64), u1 = __shfl_xor(t1, m, 64);
        float u2 = __shfl_xor(t2, m, 64), u3 = __shfl_xor(t3, m, 64);
        float u4 = __shfl_xor(t4, m, 64);
        ins5(u0, t0, t1, t2, t3, t4); ins5(u1, t0, t1, t2, t3, t4);
        ins5(u2, t0, t1, t2, t3, t4); ins5(u3, t0, t1, t2, t3, t4);
        ins5(u4, t0, t1, t2, t3, t4);
    }
    if (l == 0) {
        float sigma = bisect_sigma(t1 - t0, t2 - t0, t3 - t0, t4 - t0, TARGET_U);
        rho_u[c] = t0;
        isu[c] = 1.f / sigma;
    }
}

// Fused: one read of d -> W1 (x2), S, block colsum -> one atomic per thread.
__global__ __launch_bounds__(256) void su_pass(const float* __restrict__ d,
                                               const float* __restrict__ rho_z,
                                               const float* __restrict__ isz,
                                               const float* __restrict__ rho_u,
                                               const float* __restrict__ isu,
                                               float* __restrict__ out0,
                                               float* __restrict__ out1,
                                               float* __restrict__ out2,
                                               float* __restrict__ colsum) {
    __shared__ float sm[8][256];
    int tid = threadIdx.x, tx = tid & 31, ty = tid >> 5;
    int r0 = blockIdx.x * 64;
    int cb = 8 * tx;
    float4 rua = *(const float4*)(rho_u + cb);
    float4 rub = *(const float4*)(rho_u + cb + 4);
    float4 iua = *(const float4*)(isu + cb);
    float4 iub = *(const float4*)(isu + cb + 4);
    float ru[8] = {rua.x, rua.y, rua.z, rua.w, rub.x, rub.y, rub.z, rub.w};
    float iu[8] = {iua.x, iua.y, iua.z, iua.w, iub.x, iub.y, iub.z, iub.w};
    float cl[8] = {0.f, 0.f, 0.f, 0.f, 0.f, 0.f, 0.f, 0.f};
    #pragma unroll 1
    for (int i = 0; i < 8; ++i) {
        int r = r0 + ty * 8 + i;
        float rz = rho_z[r], sz = isz[r];
        float4 d0 = *(const float4*)(d + (size_t)r * KK + cb);
        float4 d1 = *(const float4*)(d + (size_t)r * KK + cb + 4);
        float dvv[8] = {d0.x, d0.y, d0.z, d0.w, d1.x, d1.y, d1.z, d1.w};
        float w1[8], su[8];
        float rs = 0.f;
        #pragma unroll
        for (int j = 0; j < 8; ++j) {
            w1[j] = __expf(-fmaxf(dvv[j] - rz, 0.f) * sz);
            float w2 = __expf(-fmaxf(dvv[j] - ru[j], 0.f) * iu[j]);
            su[j] = w1[j] + w2 - w1[j] * w2;
            rs += su[j];
        }
        #pragma unroll
        for (int m = 1; m < 32; m <<= 1) rs += __shfl_xor(rs, m, 64);
        float ir = 1.f / rs;
        *(float4*)(out0 + (size_t)r * KK + cb)     = make_float4(w1[0], w1[1], w1[2], w1[3]);
        *(float4*)(out0 + (size_t)r * KK + cb + 4) = make_float4(w1[4], w1[5], w1[6], w1[7]);
        *(float4*)(out2 + (size_t)r * KK + cb)     = make_float4(w1[0], w1[1], w1[2], w1[3]);
        *(float4*)(out2 + (size_t)r * KK + cb + 4) = make_float4(w1[4], w1[5], w1[6], w1[7]);
        float s[8];
        #pragma unroll
        for (int j = 0; j < 8; ++j) { s[j] = su[j] * ir; cl[j] += s[j]; }
        *(float4*)(out1 + (size_t)r * KK + cb)     = make_float4(s[0], s[1], s[2], s[3]);
        *(float4*)(out1 + (size_t)r * KK + cb + 4) = make_float4(s[4], s[5], s[6], s[7]);
    }
    #pragma unroll
    for (int j = 0; j < 8; ++j) sm[ty][cb + j] = cl[j];
    __syncthreads();
    float a = 0.f;
    #pragma unroll
    for (int g = 0; g < 8; ++g) a += sm[g][tid];
    atomicAdd(&colsum[tid], a);
}

__global__ __launch_bounds__(256) void invert256(const float* __restrict__ colsum,
                                                 float* __restrict__ icol) {
    icol[threadIdx.x] = 1.f / colsum[threadIdx.x];
}

// Fused: one read of S -> Dmat (row-normalized S^2 * icol).
__global__ __launch_bounds__(256) void dmat_fused(const float* __restrict__ S,
                                                  const float* __restrict__ icol,
                                                  float* __restrict__ out3) {
    int tid = threadIdx.x, tx = tid & 31, ty = tid >> 5;
    int r0 = blockIdx.x * 64;
    int cb = 8 * tx;
    float4 ic0 = *(const float4*)(icol + cb);
    float4 ic1 = *(const float4*)(icol + cb + 4);
    float ic[8] = {ic0.x, ic0.y, ic0.z, ic0.w, ic1.x, ic1.y, ic1.z, ic1.w};
    #pragma unroll 1
    for (int i = 0; i < 8; ++i) {
        int r = r0 + ty * 8 + i;
        float4 v0 = *(const float4*)(S + (size_t)r * KK + cb);
        float4 v1 = *(const float4*)(S + (size_t)r * KK + cb + 4);
        float sv[8] = {v0.x, v0.y, v0.z, v0.w, v1.x, v1.y, v1.z, v1.w};
        float dp[8];
        float rs = 0.f;
        #pragma unroll
        for (int j = 0; j < 8; ++j) { dp[j] = sv[j] * sv[j] * ic[j]; rs += dp[j]; }
        #pragma unroll
        for (int m = 1; m < 32; m <<= 1) rs += __shfl_xor(rs, m, 64);
        float ir = 1.f / rs;
        *(float4*)(out3 + (size_t)r * KK + cb)     = make_float4(dp[0] * ir, dp[1] * ir, dp[2] * ir, dp[3] * ir);
        *(float4*)(out3 + (size_t)r * KK + cb + 4) = make_float4(dp[4] * ir, dp[5] * ir, dp[6] * ir, dp[7] * ir);
    }
}

// ---------------- launch ----------------

extern "C" void kernel_launch(void* const* d_in, const int* in_sizes, int n_in,
                              void* d_out, int out_size, void* d_ws, size_t ws_size,
                              hipStream_t stream) {
    const float* z  = (const float*)d_in[0];
    const float* mu = (const float*)d_in[1];

    float* out = (float*)d_out;
    float* out0 = out;                 // W1
    float* out1 = out + KNK;           // S
    float* out2 = out + 2 * KNK;       // W1 (again)
    float* out3 = out + 3 * KNK;       // Dmat — d scratch first

    float* w = (float*)d_ws;
    float* zs       = w;                        // KN
    float* z2       = w + KN;                   // KN
    float* rho_z    = w + 2 * (size_t)KN;       // KN
    float* isz      = w + 3 * (size_t)KN;       // KN
    float* ms       = w + 4 * (size_t)KN;       // KK
    float* m2       = ms + KK;                  // KK
    float* rho_u    = m2 + KK;                  // KK
    float* isu      = rho_u + KK;               // KK
    float* colsum   = isu + KK;                 // KK
    float* icol     = colsum + KK;              // KK
    float* partials = icol + KK + 256;          // 256*256*5 floats

    float* dmat = out3;

    hipMemsetAsync(colsum, 0, KK * sizeof(float), stream);

    row_stats<<<KN / 4, 256, 0, stream>>>(z, zs, z2);
    row_stats<<<KK / 4, 256, 0, stream>>>(mu, ms, m2);

    dist_fused<<<KN / 64, 256, 0, stream>>>(z, mu, zs, z2, ms, m2, dmat, rho_z, isz);

    col_partial<<<KN / 256, 256, 0, stream>>>(dmat, partials);
    col_sigma<<<KK, 64, 0, stream>>>(partials, rho_u, isu);

    su_pass<<<KN / 64, 256, 0, stream>>>(dmat, rho_z, isz, rho_u, isu,
                                         out0, out1, out2, colsum);

    invert256<<<1, 256, 0, stream>>>(colsum, icol);

    dmat_fused<<<KN / 64, 256, 0, stream>>>(out1, icol, out3);
}